// Round 1
// 890.175 us; speedup vs baseline: 1.0057x; 1.0057x over previous
//
#include <hip/hip_runtime.h>
#include <stdint.h>

typedef __bf16 bf16x8 __attribute__((ext_vector_type(8)));
typedef __bf16 bf16x4 __attribute__((ext_vector_type(4)));
typedef float  floatx4 __attribute__((ext_vector_type(4)));

#define B_  16
#define LQ  2048
#define LV  2048
#define DD  512

// async global->LDS, 16B per lane; LDS dest = wave-uniform base + lane*16
__device__ __forceinline__ void gl_lds16(const void* g, void* l) {
  __builtin_amdgcn_global_load_lds(
      (const __attribute__((address_space(1))) unsigned int*)g,
      (__attribute__((address_space(3))) unsigned int*)l, 16, 0, 0);
}

// ---------- K0a: split fp32 -> (hi, lo) bf16 for Q and V, 8 elems/thread ----------
__global__ __launch_bounds__(256) void cvt_split(
    const float* __restrict__ Q, const float* __restrict__ V,
    __bf16* __restrict__ qh, __bf16* __restrict__ ql,
    __bf16* __restrict__ vh, __bf16* __restrict__ vl) {
  size_t i = ((size_t)blockIdx.x * 256 + threadIdx.x) * 8;
  float4 q0 = *(const float4*)(Q + i), q1 = *(const float4*)(Q + i + 4);
  float4 v0 = *(const float4*)(V + i), v1 = *(const float4*)(V + i + 4);
  float qa[8] = {q0.x, q0.y, q0.z, q0.w, q1.x, q1.y, q1.z, q1.w};
  float va[8] = {v0.x, v0.y, v0.z, v0.w, v1.x, v1.y, v1.z, v1.w};
  bf16x8 qhi, qlo, vhi, vlo;
#pragma unroll
  for (int j = 0; j < 8; j++) {
    __bf16 h = (__bf16)qa[j]; qhi[j] = h; qlo[j] = (__bf16)(qa[j] - (float)h);
    __bf16 g = (__bf16)va[j]; vhi[j] = g; vlo[j] = (__bf16)(va[j] - (float)g);
  }
  *(bf16x8*)(qh + i) = qhi; *(bf16x8*)(ql + i) = qlo;
  *(bf16x8*)(vh + i) = vhi; *(bf16x8*)(vl + i) = vlo;
}

// ---------- K0b: V [Lv][D] fp32 -> Vt [D][Lv] bf16 (hi only) ----------
__global__ __launch_bounds__(256) void transp_v(const float* __restrict__ V,
                                                __bf16* __restrict__ vt) {
  __shared__ float tile[32][33];
  int b = blockIdx.z;
  int v0 = blockIdx.x * 32, d0 = blockIdx.y * 32;
  int t = threadIdx.x, r = t >> 3, c4 = (t & 7) * 4;
  const float* Vb = V + (size_t)b * LV * DD;
  float4 x = *(const float4*)(Vb + (size_t)(v0 + r) * DD + d0 + c4);
  tile[r][c4] = x.x; tile[r][c4 + 1] = x.y; tile[r][c4 + 2] = x.z; tile[r][c4 + 3] = x.w;
  __syncthreads();
  bf16x4 o;
#pragma unroll
  for (int j = 0; j < 4; j++) o[j] = (__bf16)tile[c4 + j][r];
  *(bf16x4*)(vt + (size_t)b * DD * LV + (size_t)(d0 + r) * LV + v0 + c4) = o;
}

// ---------- K1 v2: S = Q V^T, 256x256 tile, 8 waves, 4-phase/K-tile schedule ----------
// Fragment-major LDS layout: frag f, lane l holds A[f*16 + (l&15)][ (l>>4)*8 .. +7 ],
// stored at L[... + f*512 + l*8]  -> every ds_read_b128 is lane-linear (0 bank conflicts).
// Double-buffered (BK=32, 4 arrays = 64KB/buf, 128KB LDS). Raw s_barrier per phase,
// single vmcnt(0) per K-tile (counted-drain pipeline), setprio(1) around MFMA cluster.
#define STAGE(k0, dstbuf) do {                                                  \
    __bf16* d0 = &L[(dstbuf) * 32768 + w * 512];                                \
    __bf16* d1 = d0 + 8 * 512;                                                  \
    gl_lds16(qhb + so0 + (k0), d0);         gl_lds16(qhb + so1 + (k0), d1);     \
    gl_lds16(qlb + so0 + (k0), d0 + 8192);  gl_lds16(qlb + so1 + (k0), d1 + 8192); \
    gl_lds16(vhb + so0 + (k0), d0 + 16384); gl_lds16(vhb + so1 + (k0), d1 + 16384); \
    gl_lds16(vlb + so0 + (k0), d0 + 24576); gl_lds16(vlb + so1 + (k0), d1 + 24576); \
  } while (0)

#define PHASE(mh, nh, EXTRA, TAILWAIT) do {                                     \
    bf16x8 ah[4], al[4], bh2[2], bl2[2];                                        \
    const __bf16* Lb = &L[bb * 32768];                                          \
    _Pragma("unroll")                                                           \
    for (int mi = 0; mi < 4; mi++) {                                            \
      int off = ((wm * 8 + (mh) * 4 + mi) * 64 + l) * 8;                        \
      ah[mi] = *(const bf16x8*)&Lb[off];                                        \
      al[mi] = *(const bf16x8*)&Lb[8192 + off];                                 \
    }                                                                           \
    _Pragma("unroll")                                                           \
    for (int ni = 0; ni < 2; ni++) {                                            \
      int off = ((wn * 4 + (nh) * 2 + ni) * 64 + l) * 8;                        \
      bh2[ni] = *(const bf16x8*)&Lb[16384 + off];                               \
      bl2[ni] = *(const bf16x8*)&Lb[24576 + off];                               \
    }                                                                           \
    EXTRA;                                                                      \
    __builtin_amdgcn_s_barrier();                                               \
    asm volatile("s_waitcnt lgkmcnt(0)" ::: "memory");                          \
    __builtin_amdgcn_sched_barrier(0);                                          \
    __builtin_amdgcn_s_setprio(1);                                              \
    _Pragma("unroll")                                                           \
    for (int mi = 0; mi < 4; mi++)                                              \
      _Pragma("unroll")                                                         \
      for (int ni = 0; ni < 2; ni++) {                                          \
        floatx4 c = acc[(mh) * 4 + mi][(nh) * 2 + ni];                          \
        c = __builtin_amdgcn_mfma_f32_16x16x32_bf16(ah[mi], bh2[ni], c, 0, 0, 0); \
        c = __builtin_amdgcn_mfma_f32_16x16x32_bf16(ah[mi], bl2[ni], c, 0, 0, 0); \
        c = __builtin_amdgcn_mfma_f32_16x16x32_bf16(al[mi], bh2[ni], c, 0, 0, 0); \
        acc[(mh) * 4 + mi][(nh) * 2 + ni] = c;                                  \
      }                                                                         \
    __builtin_amdgcn_s_setprio(0);                                              \
    TAILWAIT;                                                                   \
    __builtin_amdgcn_s_barrier();                                               \
  } while (0)

__global__ __launch_bounds__(512, 2) void gemm1_scores(
    const __bf16* __restrict__ qh, const __bf16* __restrict__ ql,
    const __bf16* __restrict__ vh, const __bf16* __restrict__ vl,
    float* __restrict__ S, float2* __restrict__ pp) {
  __shared__ __attribute__((aligned(16))) __bf16 L[2 * 4 * 8192];  // 128 KiB
  int bid = blockIdx.x;
  int swz = (bid & 7) * 128 + (bid >> 3);      // XCD swizzle; bijective (1024 % 8 == 0)
  int b = swz >> 6, rem = swz & 63, mt = rem >> 3, nt = rem & 7;
  int t = threadIdx.x, w = t >> 6, l = t & 63;
  int wm = w >> 2, wn = w & 3;                 // 2x4 wave grid, 128x64 out each
  int lr = l & 15, kg = l >> 4;

  const __bf16* qhb = qh + (size_t)b * LQ * DD + (size_t)(mt * 256) * DD;
  const __bf16* qlb = ql + (size_t)b * LQ * DD + (size_t)(mt * 256) * DD;
  const __bf16* vhb = vh + (size_t)b * LV * DD + (size_t)(nt * 256) * DD;
  const __bf16* vlb = vl + (size_t)b * LV * DD + (size_t)(nt * 256) * DD;

  // staging source offsets: thread stages frag w (rows w*16+lr) and frag 8+w
  size_t so0 = (size_t)(w * 16 + lr) * DD + kg * 8;
  size_t so1 = so0 + (size_t)128 * DD;

  floatx4 acc[8][4] = {};

  STAGE(0, 0);
  asm volatile("s_waitcnt vmcnt(0)" ::: "memory");
  __builtin_amdgcn_s_barrier();

  int bb = 0;
#pragma unroll 2
  for (int tk = 0; tk < 16; ++tk) {
    PHASE(0, 0, { if (tk < 15) STAGE((tk + 1) * 32, bb ^ 1); }, {});
    PHASE(0, 1, {}, {});
    PHASE(1, 0, {}, {});
    PHASE(1, 1, {}, { asm volatile("s_waitcnt vmcnt(0)" ::: "memory"); });
    bb ^= 1;
  }

  // C/D layout 16x16: col = lane&15, row = (lane>>4)*4 + reg
  float* Sb = S + ((size_t)b * LQ + mt * 256 + wm * 128) * LV + nt * 256 + wn * 64;
#pragma unroll
  for (int m = 0; m < 8; m++)
#pragma unroll
    for (int n = 0; n < 4; n++)
#pragma unroll
      for (int r = 0; r < 4; r++)
        Sb[(size_t)(m * 16 + kg * 4 + r) * LV + n * 16 + lr] = acc[m][n][r];

  // per-row partial softmax stats over this wave's 64-col stripe
  int stripe = nt * 4 + wn;
  float2* pb = pp + ((size_t)b * LQ + mt * 256 + wm * 128) * 32;
#pragma unroll
  for (int m = 0; m < 8; m++) {
    float pm[4], ps_[4];
#pragma unroll
    for (int r = 0; r < 4; r++) {
      float mx = fmaxf(fmaxf(acc[m][0][r], acc[m][1][r]),
                       fmaxf(acc[m][2][r], acc[m][3][r]));
#pragma unroll
      for (int s = 1; s < 16; s <<= 1) mx = fmaxf(mx, __shfl_xor(mx, s));
      float sm = 0.f;
#pragma unroll
      for (int n = 0; n < 4; n++) sm += __expf(acc[m][n][r] - mx);
#pragma unroll
      for (int s = 1; s < 16; s <<= 1) sm += __shfl_xor(sm, s);
      pm[r] = mx; ps_[r] = sm;
    }
    if (lr == 0) {
#pragma unroll
      for (int r = 0; r < 4; r++)
        pb[(size_t)(m * 16 + kg * 4 + r) * 32 + stripe] = make_float2(pm[r], ps_[r]);
    }
  }
}

// ---------- K2: fold 32 stripe-partials per row -> (max, 1/sum) ----------
__global__ __launch_bounds__(256) void combine_stats(const float2* __restrict__ pp,
                                                     float2* __restrict__ stats) {
  int r = blockIdx.x * 256 + threadIdx.x;   // 0..B*LQ-1
  const float2* p = pp + (size_t)r * 32;
  float2 v[32];
#pragma unroll
  for (int i = 0; i < 32; i++) v[i] = p[i];
  float m = -3.0e38f;
#pragma unroll
  for (int i = 0; i < 32; i++) m = fmaxf(m, v[i].x);
  float s = 0.f;
#pragma unroll
  for (int i = 0; i < 32; i++) s += v[i].y * __expf(v[i].x - m);
  stats[r] = make_float2(m, 1.0f / s);
}

// ---------- K3: attn = softmax(S) in place; ctx = attn @ V. M=64/block ----------
__global__ __launch_bounds__(256, 2) void gemm2_ctx(
    float* SA,                                    // scores in, attn out (in place)
    const __bf16* __restrict__ vt, const float2* __restrict__ stats,
    float* __restrict__ ctx) {
  __shared__ __attribute__((aligned(16))) __bf16 Ps[64 * 32];
  __shared__ __attribute__((aligned(16))) __bf16 Vts[512 * 32];
  int b = blockIdx.z, mb = blockIdx.x;
  int t = threadIdx.x, w = t >> 6, l = t & 63;
  int lr = l & 15, kg = l >> 4;
  int m0 = mb * 64;
  float* Sb = SA + ((size_t)b * LQ + m0) * LV;
  const __bf16* vtb = vt + (size_t)b * DD * LV;
  int srow = t >> 2, skcol = (t & 3) * 8;       // S-staging: 64 rows x 32 k
  float2 st = stats[b * LQ + m0 + srow];
  floatx4 acc[32] = {};
  for (int k0 = 0; k0 < LV; k0 += 32) {
#pragma unroll
    for (int i = 0; i < 8; i++) {               // Vt tile [512][32] bf16 = 32KB
      int slot = i * 256 + t;
      gl_lds16(vtb + (size_t)(slot >> 2) * LV + k0 + (slot & 3) * 8,
               Vts + (size_t)(i * 256 + w * 64) * 8);
    }
    float* sp = Sb + (size_t)srow * LV + k0 + skcol;
    float4 s0 = *(const float4*)sp, s1 = *(const float4*)(sp + 4);
    float p[8] = {s0.x, s0.y, s0.z, s0.w, s1.x, s1.y, s1.z, s1.w};
    bf16x8 pbv;
#pragma unroll
    for (int j = 0; j < 8; j++) { p[j] = __expf(p[j] - st.x) * st.y; pbv[j] = (__bf16)p[j]; }
    float4 o0 = {p[0], p[1], p[2], p[3]}, o1 = {p[4], p[5], p[6], p[7]};
    *(float4*)sp = o0; *(float4*)(sp + 4) = o1;   // attn write (in place)
    *(bf16x8*)&Ps[srow * 32 + skcol] = pbv;
    __syncthreads();
    bf16x8 a[4];
#pragma unroll
    for (int mi = 0; mi < 4; mi++) a[mi] = *(const bf16x8*)&Ps[(mi * 16 + lr) * 32 + kg * 8];
#pragma unroll
    for (int nf = 0; nf < 8; nf++) {
      bf16x8 bbv = *(const bf16x8*)&Vts[(w * 128 + nf * 16 + lr) * 32 + kg * 8];
#pragma unroll
      for (int mi = 0; mi < 4; mi++)
        acc[mi * 8 + nf] = __builtin_amdgcn_mfma_f32_16x16x32_bf16(a[mi], bbv, acc[mi * 8 + nf], 0, 0, 0);
    }
    __syncthreads();
  }
  float* Cb = ctx + ((size_t)b * LQ + m0) * DD + (size_t)(w * 128);
#pragma unroll
  for (int mi = 0; mi < 4; mi++)
#pragma unroll
    for (int nf = 0; nf < 8; nf++)
#pragma unroll
      for (int r = 0; r < 4; r++)
        Cb[(size_t)(mi * 16 + kg * 4 + r) * DD + nf * 16 + lr] = acc[mi * 8 + nf][r];
}

extern "C" void kernel_launch(void* const* d_in, const int* in_sizes, int n_in,
                              void* d_out, int out_size, void* d_ws, size_t ws_size,
                              hipStream_t stream) {
  const float* Q = (const float*)d_in[0];
  const float* V = (const float*)d_in[1];
  float* out = (float*)d_out;
  float* ctx = out;                          // [16][2048][512]
  float* SA  = out + (size_t)B_ * LQ * DD;   // [16][2048][2048]: scores, then attn
  float2* pp = (float2*)ctx;                 // stripe partials, 8MB, dead before ctx write
  char* wsp = (char*)d_ws;
  size_t nqv = (size_t)B_ * LQ * DD;         // 16,777,216 elements
  __bf16* qh = (__bf16*)wsp;
  __bf16* ql = (__bf16*)(wsp + nqv * 2);
  __bf16* vh = (__bf16*)(wsp + nqv * 4);
  __bf16* vl = (__bf16*)(wsp + nqv * 6);
  float2* stats = (float2*)(wsp + nqv * 8);  // 32768 * 8B
  __bf16* vt = qh;                           // reuse qh region after gemm1

  cvt_split<<<dim3((unsigned)(nqv / 2048)), 256, 0, stream>>>(Q, V, qh, ql, vh, vl);
  gemm1_scores<<<dim3(8 * 8 * B_), 512, 0, stream>>>(qh, ql, vh, vl, SA, pp);
  transp_v<<<dim3(LV / 32, DD / 32, B_), 256, 0, stream>>>(V, vt);
  combine_stats<<<dim3(B_ * LQ / 256), 256, 0, stream>>>(pp, stats);
  gemm2_ctx<<<dim3(LQ / 64, 1, B_), 256, 0, stream>>>(SA, vt, stats, ctx);
}